// Round 4
// baseline (434.479 us; speedup 1.0000x reference)
//
#include <hip/hip_runtime.h>

#define NIMG 512
#define H 64
#define W 64
#define C 32
#define HW (H * W)

__device__ __forceinline__ int iclamp(int v, int lo, int hi) {
    return v < lo ? lo : (v > hi ? hi : v);
}

// One block = one output row (64 pixels) of one image.
// 4 threads per pixel, each handling 8 channels (32 B fp32).
// Inputs fp32, output fp32.
__global__ __launch_bounds__(256) void stn_bilinear_kernel(
    const float* __restrict__ X,       // (N, H, W, C) fp32
    const float* __restrict__ theta,   // (N, 6) fp32
    float* __restrict__ out)           // (N, H, W, C) fp32
{
    // XCD-locality swizzle: blockIdx % 8 assumed to round-robin XCDs; give
    // each XCD a contiguous slab of 64 images so each 512 KiB fp32 source
    // image stays resident in that XCD's 4 MiB L2 while its 64 row-blocks
    // run. Heuristic only; correctness independent of mapping.
    const int b    = blockIdx.x;
    const int xcd  = b & 7;
    const int sub  = b >> 3;                 // 0..4095
    const int n    = xcd * 64 + (sub >> 6);  // image index 0..511
    const int row  = sub & 63;               // output row i
    const int col  = threadIdx.x >> 2;       // output col j
    const int quad = threadIdx.x & 3;        // channel group of 8

    // Per-image affine params (uniform across the block; scalar loads).
    const float* th = theta + n * 6;
    const double a00 = (double)th[0], a01 = (double)th[1], a02 = (double)th[2];
    const double a10 = (double)th[3], a11 = (double)th[4], a12 = (double)th[5];

    // np.linspace(-1, 1, 64) float64 semantics: step = 2/63,
    // v[j] = j*step - 1, endpoint forced to exactly 1.0.
    const double step = 2.0 / 63.0;
    const double xj = (col == W - 1) ? 1.0 : ((double)col * step - 1.0);
    const double yi = (row == H - 1) ? 1.0 : ((double)row * step - 1.0);

    // Source coords in float64 so floor/clip boundary decisions match the
    // numpy reference at gx/gy integer discontinuities.
    const double gs0 = (a00 * xj + a01 * yi) + a02;
    const double gs1 = (a10 * xj + a11 * yi) + a12;
    const double gx = (double)W * (gs0 + 1.0) * 0.5;  // *64 and /2 exact
    const double gy = (double)H * (gs1 + 1.0) * 0.5;

    double fx = floor(gx);
    double fy = floor(gy);
    fx = fmin(fmax(fx, -1.0e6), 1.0e6);  // defensive: keep int cast defined
    fy = fmin(fmax(fy, -1.0e6), 1.0e6);
    const int x0i = (int)fx;
    const int y0i = (int)fy;

    const int X0 = iclamp(x0i,     0, W - 1);
    const int X1 = iclamp(x0i + 1, 0, W - 1);
    const int Y0 = iclamp(y0i,     0, H - 1);
    const int Y1 = iclamp(y0i + 1, 0, H - 1);

    // Weight factors from CLIPPED corners (matches reference). When a
    // coordinate is clamped (X0==X1), dwax == -dwbx exactly and the two
    // corner contributions cancel to ~ulp, matching the reference's own
    // exact cancellation in float64 (residual ~1e-3 worst case, threshold
    // is 8.9e-2).
    const float dwax = (float)((double)X1 - gx);
    const float dwbx = (float)(gx - (double)X0);
    const float dway = (float)((double)Y1 - gy);
    const float dwby = (float)(gy - (double)Y0);

    const float* img = X + (size_t)n * (HW * C);
    const int cb = quad * 8;  // channel base

    const float4* pa = (const float4*)(img + (Y0 * W + X0) * C + cb);
    const float4* pb = (const float4*)(img + (Y1 * W + X0) * C + cb);
    const float4* pc = (const float4*)(img + (Y0 * W + X1) * C + cb);
    const float4* pd = (const float4*)(img + (Y1 * W + X1) * C + cb);

    float A[8], B[8], Cv[8], D[8];
    *(float4*)&A[0]  = pa[0];  *(float4*)&A[4]  = pa[1];
    *(float4*)&B[0]  = pb[0];  *(float4*)&B[4]  = pb[1];
    *(float4*)&Cv[0] = pc[0];  *(float4*)&Cv[4] = pc[1];
    *(float4*)&D[0]  = pd[0];  *(float4*)&D[4]  = pd[1];

    float r[8];
#pragma unroll
    for (int k = 0; k < 8; ++k) {
        r[k] = dwax * (dway * A[k] + dwby * B[k])
             + dwbx * (dway * Cv[k] + dwby * D[k]);
    }

    const size_t opix = (size_t)(n * HW + row * W + col);
    float* po = out + opix * C + cb;
    *(float4*)(po)     = *(const float4*)&r[0];
    *(float4*)(po + 4) = *(const float4*)&r[4];
}

extern "C" void kernel_launch(void* const* d_in, const int* in_sizes, int n_in,
                              void* d_out, int out_size, void* d_ws, size_t ws_size,
                              hipStream_t stream) {
    const float* X     = (const float*)d_in[0];
    const float* theta = (const float*)d_in[1];
    float* out         = (float*)d_out;

    const int blocks = NIMG * H;  // 32768 blocks, one output row each
    hipLaunchKernelGGL(stn_bilinear_kernel, dim3(blocks), dim3(256), 0, stream,
                       X, theta, out);
}